// Round 10
// baseline (180.505 us; speedup 1.0000x reference)
//
#include <hip/hip_runtime.h>

// B=8192, L=512, P=64, S=32, O=200
// Outputs (flat): [min1, min2, sub_min1, sub_min2, out(8192x200)]
// All GEMMs via mfma_f32_16x16x32_bf16 with split hi/lo bf16 (3-product).
// prep: frag-convert x/proto/subp + norms + init. phase1: x@protoT (k-split
// 4 waves/tile). scan: 16-sample chunks. reorder: gather sorted x-frags.
// phase3: chunk GEMM + stats + GEMV. final: scalars.

#define NL 512
#define NP 64
#define NS 32
#define NO 200
#define NB 8192
#define MAXCH 576

// float-region offsets
#define WS_SUM     0
#define WS_COLMIN  1      // uint[64]
#define WS_SUBMIN  65     // uint[2048]
#define WS_GRPSUM  2113   // float[64]
#define WS_COUNT   2177   // uint[64]
#define WS_PP      2241   // float[64]
#define WS_SP2     2305   // float[2048]
#define WS_C2G     4353   // int[576]
#define WS_CBASE   4929   // uint[576]
#define WS_CMCNT   5505   // uint[576]
#define WS_OFFS    6081   // uint[65]
#define WS_SS      6146   // float[8192]
#define WS_IDX     14338  // int[8192]
#define WS_ORDER   22530  // uint[8192] -> ends 30722 floats = 122888 B
// byte offsets, bf16 fragment arrays (16B per frag)
#define WB_PB_HI   131072    // 4096 frags
#define WB_PB_LO   196608
#define WB_SPB_HI  262144    // 131072 frags (2 MB)
#define WB_SPB_LO  2359296
#define WB_XF_HI   4456448   // 512*16*64 frags (8 MB)
#define WB_XF_LO   12845056
#define WB_XSF_HI  21233664  // 576*16*64 frags (9 MB)
#define WB_XSF_LO  30670848  // ends 40108032

typedef __attribute__((ext_vector_type(8))) short short8v;
typedef __attribute__((ext_vector_type(4))) float f32x4;

__device__ __forceinline__ unsigned encf(float f) {
  unsigned u = __float_as_uint(f);
  return (u & 0x80000000u) ? ~u : (u | 0x80000000u);
}
__device__ __forceinline__ float decf(unsigned m) {
  return __uint_as_float((m & 0x80000000u) ? (m ^ 0x80000000u) : ~m);
}
__device__ __forceinline__ float wred(float v) {
#pragma unroll
  for (int m = 32; m >= 1; m >>= 1) v += __shfl_xor(v, m, 64);
  return v;
}
__device__ __forceinline__ float dot4(const float4& a, const float4& b) {
  return a.x * b.x + a.y * b.y + a.z * b.z + a.w * b.w;
}
__device__ __forceinline__ unsigned short f2bf(float f) {
  unsigned u = __float_as_uint(f);
  u += 0x7FFFu + ((u >> 16) & 1u);
  return (unsigned short)(u >> 16);
}
__device__ __forceinline__ float bf2f(unsigned short h) {
  return __uint_as_float(((unsigned)h) << 16);
}
__device__ __forceinline__ void cvt8s(const float4& v0, const float4& v1,
                                      short8v& hi, short8v& lo) {
  float vs[8] = {v0.x, v0.y, v0.z, v0.w, v1.x, v1.y, v1.z, v1.w};
#pragma unroll
  for (int i = 0; i < 8; ++i) {
    unsigned short h = f2bf(vs[i]);
    hi[i] = (short)h;
    lo[i] = (short)f2bf(vs[i] - bf2f(h));
  }
}

// grid 1074:
//  0..511   x tiles: frags + ss
//  512..527 proto frags
//  528..1039 subp frags
//  1040..1071 sp2 norms; 1072 pp norms; 1073 init
__global__ __launch_bounds__(256) void hier_prep(const float* __restrict__ x,
                                                 const float* __restrict__ proto,
                                                 const float* __restrict__ subp,
                                                 float* __restrict__ ws) {
  __shared__ float part[256];
  const int bid = blockIdx.x, tid = threadIdx.x;

  if (bid < 512) {  // x tile
    const int tile = bid;
    short8v* xfh = (short8v*)((char*)ws + WB_XF_HI);
    short8v* xfl = (short8v*)((char*)ws + WB_XF_LO);
#pragma unroll
    for (int i = 0; i < 4; ++i) {
      const int f = i * 256 + tid;            // 0..1023
      const int kt = f >> 6, l = f & 63;
      const int row = tile * 16 + (l & 15), k0 = kt * 32 + (l >> 4) * 8;
      const float* src = x + (size_t)row * NL + k0;
      short8v hi, lo;
      cvt8s(*(const float4*)src, *(const float4*)(src + 4), hi, lo);
      const size_t fo = (size_t)(tile * 16 + kt) * 64 + l;
      xfh[fo] = hi;
      xfl[fo] = lo;
    }
    // ss: 16 threads/row x 8 float4
    {
      const int s = tid >> 4, q = tid & 15;
      const float4* xv = (const float4*)(x + (size_t)(tile * 16 + s) * NL) + q * 8;
      float a = 0.f;
#pragma unroll
      for (int j = 0; j < 8; ++j) a += dot4(xv[j], xv[j]);
      part[tid] = a;
    }
    __syncthreads();
    if (tid < 16) {
      float a = 0.f;
#pragma unroll
      for (int q = 0; q < 16; ++q) a += part[tid * 16 + q];
      ws[WS_SS + tile * 16 + tid] = a;
    }
    return;
  }
  if (bid < 528) {  // proto frags
    unsigned short* pbh = (unsigned short*)((char*)ws + WB_PB_HI);
    unsigned short* pbl = (unsigned short*)((char*)ws + WB_PB_LO);
    const int pi = (bid - 512) * 256 + tid;   // 0..4095
    const int l = pi & 63, nt = (pi >> 6) & 3, kt = pi >> 8;
    const int p = nt * 16 + (l & 15), k0 = kt * 32 + (l >> 4) * 8;
    const float* src = proto + (size_t)p * NL + k0;
    short8v hi, lo;
    cvt8s(*(const float4*)src, *(const float4*)(src + 4), hi, lo);
    ((short8v*)pbh)[pi] = hi;
    ((short8v*)pbl)[pi] = lo;
    return;
  }
  if (bid < 1040) {  // subp frags
    short8v* sph = (short8v*)((char*)ws + WB_SPB_HI);
    short8v* spl = (short8v*)((char*)ws + WB_SPB_LO);
    const int fi = (bid - 528) * 256 + tid;   // 0..131071
    const int l = fi & 63, nt = (fi >> 6) & 1, kt = (fi >> 7) & 15, g = fi >> 11;
    const int s = nt * 16 + (l & 15), k0 = kt * 32 + (l >> 4) * 8;
    const float* src = subp + ((size_t)(g * NS + s)) * NL + k0;
    short8v hi, lo;
    cvt8s(*(const float4*)src, *(const float4*)(src + 4), hi, lo);
    sph[fi] = hi;
    spl[fi] = lo;
    return;
  }
  if (bid < 1072) {  // sp2
    const int r = (bid - 1040) * 64 + (tid >> 2), q = tid & 3;
    const float4* src = (const float4*)(subp + (size_t)r * NL) + q * 32;
    float a = 0.f;
#pragma unroll
    for (int j = 0; j < 32; ++j) a += dot4(src[j], src[j]);
    part[tid] = a;
    __syncthreads();
    if (tid < 64)
      ws[WS_SP2 + (bid - 1040) * 64 + tid] =
          part[4 * tid] + part[4 * tid + 1] + part[4 * tid + 2] + part[4 * tid + 3];
    return;
  }
  if (bid == 1072) {  // pp
    const int r = tid >> 2, q = tid & 3;
    const float4* src = (const float4*)(proto + (size_t)r * NL) + q * 32;
    float a = 0.f;
#pragma unroll
    for (int j = 0; j < 32; ++j) a += dot4(src[j], src[j]);
    part[tid] = a;
    __syncthreads();
    if (tid < 64)
      ws[WS_PP + tid] =
          part[4 * tid] + part[4 * tid + 1] + part[4 * tid + 2] + part[4 * tid + 3];
    return;
  }
  // init
  unsigned* wsu = (unsigned*)ws;
  if (tid == 0) ws[WS_SUM] = 0.f;
  if (tid < 64) {
    wsu[WS_COLMIN + tid] = 0xFFFFFFFFu;
    ws[WS_GRPSUM + tid] = 0.f;
    wsu[WS_COUNT + tid] = 0u;
  }
  for (int u = tid; u < NP * NS; u += 256) wsu[WS_SUBMIN + u] = 0xFFFFFFFFu;
}

// grid 512 x 256: block = 16-sample tile; wave w = k-quarter (4 kt).
__global__ __launch_bounds__(256) void hier_phase1(float* __restrict__ ws) {
  __shared__ float accl[4][64][17];
  __shared__ float ss_l[16], pp_l[64];
  __shared__ unsigned hist_l[64];
  const int tid = threadIdx.x, lane = tid & 63, w = tid >> 6;
  const int c = lane & 15, g4 = lane >> 4;
  const int tile = blockIdx.x;
  const short8v* XFH = (const short8v*)((const char*)ws + WB_XF_HI);
  const short8v* XFL = (const short8v*)((const char*)ws + WB_XF_LO);
  const short8v* PBH = (const short8v*)((const char*)ws + WB_PB_HI);
  const short8v* PBL = (const short8v*)((const char*)ws + WB_PB_LO);

  if (tid < 16) ss_l[tid] = ws[WS_SS + tile * 16 + tid];
  if (tid < 64) { pp_l[tid] = ws[WS_PP + tid]; hist_l[tid] = 0u; }

  f32x4 acc[4];
#pragma unroll
  for (int nt = 0; nt < 4; ++nt) acc[nt] = (f32x4){0.f, 0.f, 0.f, 0.f};
#pragma unroll
  for (int i = 0; i < 4; ++i) {
    const int kt = w * 4 + i;
    short8v ah = XFH[(size_t)(tile * 16 + kt) * 64 + lane];
    short8v al = XFL[(size_t)(tile * 16 + kt) * 64 + lane];
#pragma unroll
    for (int nt = 0; nt < 4; ++nt) {
      short8v bh = PBH[(size_t)(kt * 4 + nt) * 64 + lane];
      short8v bl = PBL[(size_t)(kt * 4 + nt) * 64 + lane];
      acc[nt] = __builtin_amdgcn_mfma_f32_16x16x32_bf16(ah, bh, acc[nt], 0, 0, 0);
      acc[nt] = __builtin_amdgcn_mfma_f32_16x16x32_bf16(ah, bl, acc[nt], 0, 0, 0);
      acc[nt] = __builtin_amdgcn_mfma_f32_16x16x32_bf16(al, bh, acc[nt], 0, 0, 0);
    }
  }
#pragma unroll
  for (int nt = 0; nt < 4; ++nt)
#pragma unroll
    for (int r = 0; r < 4; ++r) accl[w][lane][nt * 4 + r] = acc[nt][r];
  __syncthreads();

  if (w == 0) {
    float dv[4][4];
#pragma unroll
    for (int nt = 0; nt < 4; ++nt) {
      const float ppv = pp_l[nt * 16 + c];
#pragma unroll
      for (int r = 0; r < 4; ++r) {
        const int j = nt * 4 + r;
        float s = accl[0][lane][j] + accl[1][lane][j] + accl[2][lane][j] +
                  accl[3][lane][j];
        dv[nt][r] = ss_l[g4 * 4 + r] + ppv - 2.f * s;
      }
    }
    float rmin[4];
    int rarg[4];
#pragma unroll
    for (int r = 0; r < 4; ++r) {
      rmin[r] = 1e30f; rarg[r] = 0;
#pragma unroll
      for (int nt = 0; nt < 4; ++nt)
        if (dv[nt][r] < rmin[r]) { rmin[r] = dv[nt][r]; rarg[r] = nt * 16 + c; }
    }
#pragma unroll
    for (int m = 1; m <= 8; m <<= 1) {
#pragma unroll
      for (int r = 0; r < 4; ++r) {
        float om = __shfl_xor(rmin[r], m, 64);
        int oa = __shfl_xor(rarg[r], m, 64);
        if (om < rmin[r] || (om == rmin[r] && oa < rarg[r])) { rmin[r] = om; rarg[r] = oa; }
      }
    }
#pragma unroll
    for (int nt = 0; nt < 4; ++nt) {
      float cm = fminf(fminf(dv[nt][0], dv[nt][1]), fminf(dv[nt][2], dv[nt][3]));
      cm = fminf(cm, __shfl_xor(cm, 16, 64));
      cm = fminf(cm, __shfl_xor(cm, 32, 64));
      if (lane < 16) atomicMin((unsigned*)ws + WS_COLMIN + nt * 16 + lane, encf(cm));
    }
    float rsum = 0.f;
    if (c == 0) {
#pragma unroll
      for (int r = 0; r < 4; ++r) {
        ((int*)ws)[WS_IDX + tile * 16 + g4 * 4 + r] = rarg[r];
        atomicAdd(&hist_l[rarg[r]], 1u);
        rsum += rmin[r];
      }
    }
    rsum = wred(rsum);
    if (lane == 0) atomicAdd(&ws[WS_SUM], rsum);
  }
  __syncthreads();
  if (tid < 64 && hist_l[tid]) atomicAdd((unsigned*)ws + WS_COUNT + tid, hist_l[tid]);
}

// 1 block x 256: offsets, 16-sample chunk records, scatter-sort by group.
__global__ __launch_bounds__(256) void hier_scan(float* __restrict__ ws) {
  __shared__ unsigned cnt_l[64];
  __shared__ unsigned cur[64];
  const int tid = threadIdx.x;
  unsigned* wsu = (unsigned*)ws;
  for (int i = tid; i < MAXCH; i += 256) ((int*)ws)[WS_C2G + i] = -1;
  if (tid < 64) cnt_l[tid] = wsu[WS_COUNT + tid];
  __syncthreads();
  if (tid == 0) {
    unsigned run = 0;
    int nc = 0;
    for (int g = 0; g < NP; ++g) {
      wsu[WS_OFFS + g] = run;
      unsigned cc = cnt_l[g];
      for (unsigned j = 0; j * 16 < cc; ++j) {
        ((int*)ws)[WS_C2G + nc] = g;
        wsu[WS_CBASE + nc] = run + j * 16;
        unsigned mc = cc - j * 16;
        wsu[WS_CMCNT + nc] = mc < 16u ? mc : 16u;
        ++nc;
      }
      run += cc;
    }
    wsu[WS_OFFS + 64] = run;
  }
  __syncthreads();
  if (tid < 64) cur[tid] = wsu[WS_OFFS + tid];
  __syncthreads();
  const int* idx = (const int*)ws + WS_IDX;
  for (int b = tid; b < NB; b += 256) {
    int g = idx[b];
    unsigned pos = atomicAdd(&cur[g], 1u);
    wsu[WS_ORDER + pos] = (unsigned)b;
  }
}

// grid 576 x 256: gather sorted x-frags (padded) into XSF, coalesced writes.
__global__ __launch_bounds__(256) void hier_reorder(float* __restrict__ ws) {
  const int ch = blockIdx.x, tid = threadIdx.x;
  if (((const int*)ws)[WS_C2G + ch] < 0) return;
  const unsigned base = ((const unsigned*)ws)[WS_CBASE + ch];
  const int mc = (int)((const unsigned*)ws)[WS_CMCNT + ch];
  const unsigned* order = (const unsigned*)ws + WS_ORDER;
  const uint4* XFH = (const uint4*)((const char*)ws + WB_XF_HI);
  const uint4* XFL = (const uint4*)((const char*)ws + WB_XF_LO);
  uint4* XSFH = (uint4*)((char*)ws + WB_XSF_HI);
  uint4* XSFL = (uint4*)((char*)ws + WB_XSF_LO);
#pragma unroll
  for (int i = 0; i < 4; ++i) {
    const int f = i * 256 + tid;  // 0..1023
    const int kt = f >> 6, l = f & 63;
    int m = l & 15;
    if (m >= mc) m = mc - 1;
    const unsigned row = order[base + m];
    const size_t src = (size_t)((row >> 4) * 16 + kt) * 64 + ((l >> 4) * 16 + (row & 15));
    const size_t dst = (size_t)(ch * 16 + kt) * 64 + l;
    XSFH[dst] = XFH[src];
    XSFL[dst] = XFL[src];
  }
}

// grid 576 x 256: block = 16-sample single-group chunk; wave = k-quarter.
__global__ __launch_bounds__(256) void hier_phase3(const float* __restrict__ Wm,
                                                   const float* __restrict__ bias,
                                                   float* __restrict__ out,
                                                   float* __restrict__ ws) {
  __shared__ float accl[4][64][9];
  __shared__ float ss_l[16], sp2_l[32];
  __shared__ unsigned rows_l[16];
  __shared__ float dsel_l[16][36];
  const int tid = threadIdx.x, lane = tid & 63, w = tid >> 6;
  const int c = lane & 15, g4 = lane >> 4;
  const int ch = blockIdx.x;
  const int graw = ((const int*)ws)[WS_C2G + ch];
  if (graw < 0) return;
  const int g = graw;
  const unsigned base = ((const unsigned*)ws)[WS_CBASE + ch];
  const int mc = (int)((const unsigned*)ws)[WS_CMCNT + ch];

  // hoist expert row (thread t -> output o=t)
  float4 wreg[8];
  float breg = 0.f;
  if (tid < NO) {
    const float4* wr = (const float4*)(Wm + ((size_t)g * NO + tid) * NS);
#pragma unroll
    for (int k = 0; k < 8; ++k) wreg[k] = wr[k];
    breg = bias[(size_t)g * NO + tid];
  }

  if (tid < 16) {
    int m = tid < mc ? tid : mc - 1;
    unsigned r = ((const unsigned*)ws)[WS_ORDER + base + m];
    rows_l[tid] = r;
    ss_l[tid] = ws[WS_SS + r];
  }
  if (tid < 32) sp2_l[tid] = ws[WS_SP2 + g * NS + tid];

  const short8v* XSFH = (const short8v*)((const char*)ws + WB_XSF_HI);
  const short8v* XSFL = (const short8v*)((const char*)ws + WB_XSF_LO);
  const short8v* SPH = (const short8v*)((const char*)ws + WB_SPB_HI);
  const short8v* SPL = (const short8v*)((const char*)ws + WB_SPB_LO);

  f32x4 acc[2];
  acc[0] = (f32x4){0.f, 0.f, 0.f, 0.f};
  acc[1] = (f32x4){0.f, 0.f, 0.f, 0.f};
#pragma unroll
  for (int i = 0; i < 4; ++i) {
    const int kt = w * 4 + i;
    short8v ah = XSFH[(size_t)(ch * 16 + kt) * 64 + lane];
    short8v al = XSFL[(size_t)(ch * 16 + kt) * 64 + lane];
#pragma unroll
    for (int nt = 0; nt < 2; ++nt) {
      short8v bh = SPH[((size_t)(g * 16 + kt) * 2 + nt) * 64 + lane];
      short8v bl = SPL[((size_t)(g * 16 + kt) * 2 + nt) * 64 + lane];
      acc[nt] = __builtin_amdgcn_mfma_f32_16x16x32_bf16(ah, bh, acc[nt], 0, 0, 0);
      acc[nt] = __builtin_amdgcn_mfma_f32_16x16x32_bf16(ah, bl, acc[nt], 0, 0, 0);
      acc[nt] = __builtin_amdgcn_mfma_f32_16x16x32_bf16(al, bh, acc[nt], 0, 0, 0);
    }
  }
#pragma unroll
  for (int nt = 0; nt < 2; ++nt)
#pragma unroll
    for (int r = 0; r < 4; ++r) accl[w][lane][nt * 4 + r] = acc[nt][r];
  __syncthreads();

  if (w == 0) {
    float dv[2][4];
#pragma unroll
    for (int nt = 0; nt < 2; ++nt) {
      const float s2 = sp2_l[nt * 16 + c];
#pragma unroll
      for (int r = 0; r < 4; ++r) {
        const int j = nt * 4 + r;
        float s = accl[0][lane][j] + accl[1][lane][j] + accl[2][lane][j] +
                  accl[3][lane][j];
        dv[nt][r] = ss_l[g4 * 4 + r] + s2 - 2.f * s;
        dsel_l[g4 * 4 + r][nt * 16 + c] = dv[nt][r];
      }
    }
#pragma unroll
    for (int nt = 0; nt < 2; ++nt) {
      float cm = fminf(fminf(dv[nt][0], dv[nt][1]), fminf(dv[nt][2], dv[nt][3]));
      cm = fminf(cm, __shfl_xor(cm, 16, 64));
      cm = fminf(cm, __shfl_xor(cm, 32, 64));
      if (lane < 16)
        atomicMin((unsigned*)ws + WS_SUBMIN + g * NS + nt * 16 + lane, encf(cm));
    }
    float rmin[4];
#pragma unroll
    for (int r = 0; r < 4; ++r) rmin[r] = fminf(dv[0][r], dv[1][r]);
#pragma unroll
    for (int m = 1; m <= 8; m <<= 1)
#pragma unroll
      for (int r = 0; r < 4; ++r) rmin[r] = fminf(rmin[r], __shfl_xor(rmin[r], m, 64));
    float rsum = 0.f;
    if (c == 0) {
#pragma unroll
      for (int r = 0; r < 4; ++r) {
        const int sm = g4 * 4 + r;
        if (sm < mc) rsum += rmin[r];
      }
    }
    rsum = wred(rsum);
    if (lane == 0) atomicAdd(&ws[WS_GRPSUM + g], rsum);
  }
  __syncthreads();

  // GEMV: thread t -> output o=t, loop samples; dsel broadcast from LDS.
  if (tid < NO) {
    for (int m = 0; m < mc; ++m) {
      const float* ds = &dsel_l[m][0];
      float a = breg;
#pragma unroll
      for (int k = 0; k < 8; ++k) {
        a += ds[4 * k + 0] * wreg[k].x + ds[4 * k + 1] * wreg[k].y +
             ds[4 * k + 2] * wreg[k].z + ds[4 * k + 3] * wreg[k].w;
      }
      out[(size_t)rows_l[m] * NO + tid] = a;
    }
  }
}

__global__ void hier_final(const float* __restrict__ ws, float* __restrict__ out4) {
  const int lane = threadIdx.x;  // 64 threads
  const unsigned* colmin = (const unsigned*)ws + WS_COLMIN;
  const unsigned* submin = (const unsigned*)ws + WS_SUBMIN;
  const float* grp_sum = ws + WS_GRPSUM;
  const unsigned* counts = (const unsigned*)ws + WS_COUNT;

  float min2 = wred(decf(colmin[lane])) * (1.0f / NP);

  unsigned cnt = counts[lane];
  float s32 = 0.f;
#pragma unroll
  for (int s = 0; s < NS; s++) s32 += decf(submin[lane * NS + s]);
  float sub1 = wred((cnt > 0u) ? s32 * (1.0f / NS) : 0.f) * (1.0f / NP);
  float sub2 = wred((cnt > 0u) ? grp_sum[lane] / (float)cnt : 0.f) * (1.0f / NP);

  if (lane == 0) {
    out4[0] = ws[WS_SUM] * (1.0f / NB);
    out4[1] = min2;
    out4[2] = sub1;
    out4[3] = sub2;
  }
}

extern "C" void kernel_launch(void* const* d_in, const int* in_sizes, int n_in,
                              void* d_out, int out_size, void* d_ws, size_t ws_size,
                              hipStream_t stream) {
  const float* x = (const float*)d_in[0];
  const float* proto = (const float*)d_in[1];
  const float* subp = (const float*)d_in[2];
  const float* Wm = (const float*)d_in[3];
  const float* bias = (const float*)d_in[4];
  float* outf = (float*)d_out;
  float* ws = (float*)d_ws;

  hipLaunchKernelGGL(hier_prep, dim3(1074), dim3(256), 0, stream, x, proto, subp, ws);
  hipLaunchKernelGGL(hier_phase1, dim3(512), dim3(256), 0, stream, ws);
  hipLaunchKernelGGL(hier_scan, dim3(1), dim3(256), 0, stream, ws);
  hipLaunchKernelGGL(hier_reorder, dim3(MAXCH), dim3(256), 0, stream, ws);
  hipLaunchKernelGGL(hier_phase3, dim3(MAXCH), dim3(256), 0, stream,
                     Wm, bias, outf + 4, ws);
  hipLaunchKernelGGL(hier_final, dim3(1), dim3(64), 0, stream, ws, outf);
}